// Round 1
// baseline (676.875 us; speedup 1.0000x reference)
//
#include <hip/hip_runtime.h>
#include <math.h>

namespace {

constexpr int C = 128;       // channels
constexpr int K = 32;        // max degree
constexpr int TILE_M = 128;  // GEMM row tile
constexpr int LDSP = 132;    // LDS row stride in floats (128 + 4 pad, 16B-aligned)

// ---------------------------------------------------------------------------
// Kernel 0: inv_sqrt_deg[n] = 1/sqrt(1 + count(edge[n][k] >= 0))
// 8 nodes per 256-thread block; 32 lanes per node.
// ---------------------------------------------------------------------------
__global__ __launch_bounds__(256) void deg_kernel(const int* __restrict__ edge,
                                                  float* __restrict__ invs, int N) {
    int t = threadIdx.x;
    int node = blockIdx.x * 8 + (t >> 5);
    int k = t & 31;
    int e = (node < N) ? edge[(size_t)node * K + k] : -1;
    unsigned long long m = __ballot(e >= 0);
    int lane = t & 63;
    unsigned int half = (lane < 32) ? (unsigned int)(m & 0xffffffffULL)
                                    : (unsigned int)(m >> 32);
    int cnt = __popc(half);
    if (k == 0 && node < N) invs[node] = 1.0f / sqrtf((float)(cnt + 1));
}

// ---------------------------------------------------------------------------
// Kernel 1: H[n][o] = (sum_i X[n][i] * W[o][i]) * invs[n]
// fp32 vector-ALU GEMM (no fp32 MFMA on CDNA4).
// 256 threads, 128x128 output tile, 8x8 per thread (rows/cols strided by 16
// so LDS reads are bank-conflict-free: a-reads broadcast across 16 lanes,
// b-reads 2-way max).
// LDS: Xs 128x132 + Ws 128x132 = 132 KB (< 160 KB/CU).
// ---------------------------------------------------------------------------
__global__ __launch_bounds__(256) void gemm_scale_kernel(
    const float* __restrict__ X, const float* __restrict__ W,
    const float* __restrict__ invs, float* __restrict__ H, int N) {
    __shared__ float Xs[TILE_M * LDSP];
    __shared__ float Ws[C * LDSP];

    int t = threadIdx.x;
    int n0 = blockIdx.x * TILE_M;

    // Stage W (128x128 floats = 4096 float4; 16 per thread), coalesced.
    for (int p = t; p < C * C / 4; p += 256) {
        int row = p >> 5;   // p / 32
        int c4 = p & 31;
        float4 v = ((const float4*)W)[p];
        *(float4*)&Ws[row * LDSP + c4 * 4] = v;
    }
    // Stage X tile (rows n0..n0+127), zero-pad out-of-range rows.
    for (int p = t; p < TILE_M * C / 4; p += 256) {
        int row = p >> 5;
        int c4 = p & 31;
        int n = n0 + row;
        float4 v = make_float4(0.f, 0.f, 0.f, 0.f);
        if (n < N) v = ((const float4*)X)[(size_t)n * (C / 4) + c4];
        *(float4*)&Xs[row * LDSP + c4 * 4] = v;
    }
    __syncthreads();

    int tx = t & 15;   // col base: cols tx + 16*c
    int ty = t >> 4;   // row base: rows ty + 16*r
    float acc[8][8];
#pragma unroll
    for (int r = 0; r < 8; ++r)
#pragma unroll
        for (int c = 0; c < 8; ++c) acc[r][c] = 0.f;

#pragma unroll 4
    for (int i = 0; i < C; i += 4) {
        float4 a[8], b[8];
#pragma unroll
        for (int r = 0; r < 8; ++r)
            a[r] = *(const float4*)&Xs[(ty + r * 16) * LDSP + i];
#pragma unroll
        for (int c = 0; c < 8; ++c)
            b[c] = *(const float4*)&Ws[(tx + c * 16) * LDSP + i];
#pragma unroll
        for (int r = 0; r < 8; ++r)
#pragma unroll
            for (int c = 0; c < 8; ++c) {
                acc[r][c] += a[r].x * b[c].x;
                acc[r][c] += a[r].y * b[c].y;
                acc[r][c] += a[r].z * b[c].z;
                acc[r][c] += a[r].w * b[c].w;
            }
    }

#pragma unroll
    for (int r = 0; r < 8; ++r) {
        int n = n0 + ty + r * 16;
        if (n < N) {
            float s = invs[n];
#pragma unroll
            for (int c = 0; c < 8; ++c) {
                H[(size_t)n * C + tx + c * 16] = acc[r][c] * s;
            }
        }
    }
}

// ---------------------------------------------------------------------------
// Kernel 2: out[n][:] = elu((sum_k H[edge[n][k]][:] + H[n][:]) * invs[n])
// 8 nodes per 256-thread block; 32 lanes per node, float4 per lane (128 ch).
// Gathered rows are 512 B contiguous -> coalesced; h is L2/L3-resident.
// ---------------------------------------------------------------------------
__global__ __launch_bounds__(256) void gather_elu_kernel(
    const float* __restrict__ H, const int* __restrict__ edge,
    const float* __restrict__ invs, float* __restrict__ out, int N) {
    __shared__ int idx[8][K];
    int t = threadIdx.x;
    int g = t >> 5;
    int lane32 = t & 31;
    int node = blockIdx.x * 8 + g;

    idx[g][lane32] = (node < N) ? edge[(size_t)node * K + lane32] : -1;
    __syncthreads();
    if (node >= N) return;

    float4 acc = make_float4(0.f, 0.f, 0.f, 0.f);
#pragma unroll
    for (int k = 0; k < K; ++k) {
        int j = idx[g][k];
        if (j >= 0) {
            float4 v = *(const float4*)(H + (size_t)j * C + lane32 * 4);
            acc.x += v.x;
            acc.y += v.y;
            acc.z += v.z;
            acc.w += v.w;
        }
    }
    float4 self = *(const float4*)(H + (size_t)node * C + lane32 * 4);
    float s = invs[node];
    float4 r;
    r.x = (acc.x + self.x) * s;
    r.y = (acc.y + self.y) * s;
    r.z = (acc.z + self.z) * s;
    r.w = (acc.w + self.w) * s;
    // ELU (alpha=1)
    r.x = r.x > 0.f ? r.x : expm1f(r.x);
    r.y = r.y > 0.f ? r.y : expm1f(r.y);
    r.z = r.z > 0.f ? r.z : expm1f(r.z);
    r.w = r.w > 0.f ? r.w : expm1f(r.w);
    *(float4*)(out + (size_t)node * C + lane32 * 4) = r;
}

}  // namespace

extern "C" void kernel_launch(void* const* d_in, const int* in_sizes, int n_in,
                              void* d_out, int out_size, void* d_ws, size_t ws_size,
                              hipStream_t stream) {
    const float* x = (const float*)d_in[0];
    const int* edge = (const int*)d_in[1];
    const float* W1 = (const float*)d_in[2];
    const float* W2 = (const float*)d_in[3];
    float* out = (float*)d_out;
    const int N = in_sizes[0] / C;  // 100000

    // Workspace layout: invs [N floats] | h [N*C floats]
    char* ws = (char*)d_ws;
    float* invs = (float*)ws;
    size_t invs_bytes = ((size_t)N * sizeof(float) + 255) & ~(size_t)255;
    float* h = (float*)(ws + invs_bytes);

    const int nodeBlocks = (N + 7) / 8;
    const int gemmBlocks = (N + TILE_M - 1) / TILE_M;

    deg_kernel<<<nodeBlocks, 256, 0, stream>>>(edge, invs, N);
    // Layer 1
    gemm_scale_kernel<<<gemmBlocks, 256, 0, stream>>>(x, W1, invs, h, N);
    gather_elu_kernel<<<nodeBlocks, 256, 0, stream>>>(h, edge, invs, out, N);
    // Layer 2 (reads layer-1 activation from d_out, reuses h buffer)
    gemm_scale_kernel<<<gemmBlocks, 256, 0, stream>>>(out, W2, invs, h, N);
    gather_elu_kernel<<<nodeBlocks, 256, 0, stream>>>(h, edge, invs, out, N);
}

// Round 2
// 368.474 us; speedup vs baseline: 1.8370x; 1.8370x over previous
//
#include <hip/hip_runtime.h>
#include <hip/hip_bf16.h>
#include <math.h>

namespace {

constexpr int C = 128;       // channels
constexpr int K = 32;        // max degree
constexpr int TILE_M = 128;  // GEMM row tile
constexpr int LDSW = 132;    // LDS row stride in floats (128 + 4 pad)

__device__ __forceinline__ float bf2f(unsigned short u) {
    return __uint_as_float(((unsigned int)u) << 16);
}

// ---------------------------------------------------------------------------
// Kernel 0: inv_sqrt_deg[n] = 1/sqrt(1 + count(edge[n][k] >= 0))
// ---------------------------------------------------------------------------
__global__ __launch_bounds__(256) void deg_kernel(const int* __restrict__ edge,
                                                  float* __restrict__ invs, int N) {
    int t = threadIdx.x;
    int node = blockIdx.x * 8 + (t >> 5);
    int k = t & 31;
    int e = (node < N) ? edge[(size_t)node * K + k] : -1;
    unsigned long long m = __ballot(e >= 0);
    int lane = t & 63;
    unsigned int half = (lane < 32) ? (unsigned int)(m & 0xffffffffULL)
                                    : (unsigned int)(m >> 32);
    int cnt = __popc(half);
    if (k == 0 && node < N) invs[node] = 1.0f / sqrtf((float)(cnt + 1));
}

// ---------------------------------------------------------------------------
// Kernel 1: H[n][o] = bf16( (sum_i X[n][i] * W[o][i]) * invs[n] )
// fp32 vector-ALU GEMM. Only W staged in LDS (67.6 KB -> 2 blocks/CU,
// 2 waves/SIMD). X read directly from global: per k-chunk the block touches
// a 2 KB slice of its 128-row X tile -> L1-resident, 16-lane broadcast.
// 256 threads, 128x128 tile, 8x8 per thread strided by 16 (conflict-free
// LDS reads thanks to the +4 pad: bank advances by 1 per row group).
// ---------------------------------------------------------------------------
__global__ __launch_bounds__(256) void gemm_scale_kernel(
    const float* __restrict__ X, const float* __restrict__ W,
    const float* __restrict__ invs, unsigned short* __restrict__ H, int N) {
    __shared__ float Ws[C * LDSW];

    int t = threadIdx.x;
    int n0 = blockIdx.x * TILE_M;

    // Stage W (128x128 floats = 4096 float4; 16 per thread), coalesced.
    for (int p = t; p < C * C / 4; p += 256) {
        int row = p >> 5;
        int c4 = p & 31;
        float4 v = ((const float4*)W)[p];
        *(float4*)&Ws[row * LDSW + c4 * 4] = v;
    }
    __syncthreads();

    int tx = t & 15;   // col base: cols tx + 16*c
    int ty = t >> 4;   // row base: rows ty + 16*r

    // Row pointers, clamped so OOB rows read row N-1 (writes are guarded).
    const float* xrow[8];
#pragma unroll
    for (int r = 0; r < 8; ++r) {
        int n = n0 + ty + r * 16;
        if (n > N - 1) n = N - 1;
        xrow[r] = X + (size_t)n * C;
    }

    float acc[8][8];
#pragma unroll
    for (int r = 0; r < 8; ++r)
#pragma unroll
        for (int c = 0; c < 8; ++c) acc[r][c] = 0.f;

#pragma unroll 2
    for (int i = 0; i < C; i += 4) {
        float4 a[8], b[8];
#pragma unroll
        for (int r = 0; r < 8; ++r)
            a[r] = *(const float4*)(xrow[r] + i);
#pragma unroll
        for (int c = 0; c < 8; ++c)
            b[c] = *(const float4*)&Ws[(tx + c * 16) * LDSW + i];
#pragma unroll
        for (int r = 0; r < 8; ++r)
#pragma unroll
            for (int c = 0; c < 8; ++c) {
                acc[r][c] += a[r].x * b[c].x;
                acc[r][c] += a[r].y * b[c].y;
                acc[r][c] += a[r].z * b[c].z;
                acc[r][c] += a[r].w * b[c].w;
            }
    }

#pragma unroll
    for (int r = 0; r < 8; ++r) {
        int n = n0 + ty + r * 16;
        if (n < N) {
            float s = invs[n];
#pragma unroll
            for (int c = 0; c < 8; ++c) {
                __hip_bfloat16 hv = __float2bfloat16(acc[r][c] * s);
                H[(size_t)n * C + tx + c * 16] = *(unsigned short*)&hv;
            }
        }
    }
}

// ---------------------------------------------------------------------------
// Kernel 2: out[n][:] = elu((sum_k H[edge[n][k]][:] + H[n][:]) * invs[n])
// H is bf16 (256 B/row): 32 lanes/node x ushort4 (8 B) per neighbor row.
// Accumulation in fp32; output fp32.
// ---------------------------------------------------------------------------
__global__ __launch_bounds__(256) void gather_elu_kernel(
    const unsigned short* __restrict__ H, const int* __restrict__ edge,
    const float* __restrict__ invs, float* __restrict__ out, int N) {
    __shared__ int idx[8][K];
    int t = threadIdx.x;
    int g = t >> 5;
    int lane32 = t & 31;
    int node = blockIdx.x * 8 + g;

    idx[g][lane32] = (node < N) ? edge[(size_t)node * K + lane32] : -1;
    __syncthreads();
    if (node >= N) return;

    float a0 = 0.f, a1 = 0.f, a2 = 0.f, a3 = 0.f;
#pragma unroll
    for (int k = 0; k < K; ++k) {
        int j = idx[g][k];
        if (j >= 0) {
            ushort4 v = *(const ushort4*)(H + (size_t)j * C + lane32 * 4);
            a0 += bf2f(v.x);
            a1 += bf2f(v.y);
            a2 += bf2f(v.z);
            a3 += bf2f(v.w);
        }
    }
    ushort4 sv = *(const ushort4*)(H + (size_t)node * C + lane32 * 4);
    float s = invs[node];
    float4 r;
    r.x = (a0 + bf2f(sv.x)) * s;
    r.y = (a1 + bf2f(sv.y)) * s;
    r.z = (a2 + bf2f(sv.z)) * s;
    r.w = (a3 + bf2f(sv.w)) * s;
    // ELU (alpha=1)
    r.x = r.x > 0.f ? r.x : expm1f(r.x);
    r.y = r.y > 0.f ? r.y : expm1f(r.y);
    r.z = r.z > 0.f ? r.z : expm1f(r.z);
    r.w = r.w > 0.f ? r.w : expm1f(r.w);
    *(float4*)(out + (size_t)node * C + lane32 * 4) = r;
}

}  // namespace

extern "C" void kernel_launch(void* const* d_in, const int* in_sizes, int n_in,
                              void* d_out, int out_size, void* d_ws, size_t ws_size,
                              hipStream_t stream) {
    const float* x = (const float*)d_in[0];
    const int* edge = (const int*)d_in[1];
    const float* W1 = (const float*)d_in[2];
    const float* W2 = (const float*)d_in[3];
    float* out = (float*)d_out;
    const int N = in_sizes[0] / C;  // 100000

    // Workspace layout: invs [N floats] | h [N*C bf16]
    char* ws = (char*)d_ws;
    float* invs = (float*)ws;
    size_t invs_bytes = ((size_t)N * sizeof(float) + 255) & ~(size_t)255;
    unsigned short* h = (unsigned short*)(ws + invs_bytes);

    const int nodeBlocks = (N + 7) / 8;
    const int gemmBlocks = (N + TILE_M - 1) / TILE_M;

    deg_kernel<<<nodeBlocks, 256, 0, stream>>>(edge, invs, N);
    // Layer 1
    gemm_scale_kernel<<<gemmBlocks, 256, 0, stream>>>(x, W1, invs, h, N);
    gather_elu_kernel<<<nodeBlocks, 256, 0, stream>>>(h, edge, invs, out, N);
    // Layer 2 (reads layer-1 activation from d_out, reuses h buffer)
    gemm_scale_kernel<<<gemmBlocks, 256, 0, stream>>>(out, W2, invs, h, N);
    gather_elu_kernel<<<nodeBlocks, 256, 0, stream>>>(h, edge, invs, out, N);
}